// Round 8
// baseline (229.358 us; speedup 1.0000x reference)
//
#include <hip/hip_runtime.h>
#include <hip/hip_bf16.h>
#include <math.h>

#define NS 4096      // samples
#define NC 512       // clusters
#define ND 64        // feature dim
#define NK 10        // classes
#define NPAIR 2080   // upper-triangle pairs (e<=d) of 64x64
#define KP 2176      // 2080 + 64 (linear) + 1 (const) + 31 zero-pad; 68*32
#define BOFF 2080
#define KOFF 2144
#define KSPLIT 4
#define KT_PER (KP / 32 / KSPLIT)   // 17 k-chunks per split block

typedef __attribute__((ext_vector_type(8))) short short8;
typedef __attribute__((ext_vector_type(8))) unsigned short ushort8;
typedef __attribute__((ext_vector_type(4))) float floatx4;

__device__ inline unsigned short f2b(float x) {
    __hip_bfloat16 h = __float2bfloat16(x);           // RNE
    return __builtin_bit_cast(unsigned short, h);
}
__device__ inline float b2f(unsigned short u) {
    __hip_bfloat16 h = __builtin_bit_cast(__hip_bfloat16, u);
    return __bfloat162float(h);
}

// ---------------- pair-index tables ----------------
__global__ void table_kernel(int* __restrict__ eop, int* __restrict__ dop) {
    const int e = threadIdx.x;                        // 64 threads
    int off = e * 64 - (e * (e - 1)) / 2;             // row e starts here
    for (int d = e; d < 64; ++d) { eop[off + d - e] = e; dop[off + d - e] = d; }
}

// ---------------- Sigma^-1: register-resident wave GJ + fused beta-pack ------
// Lane j holds column j in 64 VGPRs. Sign identity (R7-verified): the in-place
// GJ intermediate of a symmetric matrix satisfies M[k][j] = (j<k?-1:+1)*M[j][k],
// so the row-k element comes from the published column-k LDS buffer at own-lane
// index (static register indexing only).
// R7 failure mode: `A[i] = (i==k) ? rowk : res` canonicalizes to a store at
// dynamic index k -> alloca kept -> scratch (VGPR=72, 90us). Fix: arithmetic
// mask  A[i] = res + mk*(rowk-res)  with mk in {0,1}. Without fast-math the
// fmul/fadd cannot be refolded into a select, so SROA keeps A[] in VGPRs.
__global__ __launch_bounds__(64, 1) void prep_kernel(
    const float* __restrict__ S, const float* __restrict__ n,
    const float* __restrict__ mu, const int* __restrict__ clab,
    const int* __restrict__ eop, const int* __restrict__ dop,
    unsigned short* __restrict__ Bph, unsigned short* __restrict__ Bpl,
    float* __restrict__ labf)
{
    const int c = blockIdx.x;
    const int j = threadIdx.x;                        // column owned by this lane
    __shared__ float colk[ND];                        // column-k broadcast
    __shared__ float Acol[ND][ND + 1];                // Sinv mirror for pack
    __shared__ float cbuf[ND];                        // bvec staging

    const float inv_nc = 1.0f / n[c];
    float A[ND];                                      // A[i] = Sigma[i][j]
    #pragma unroll
    for (int i = 0; i < ND; ++i) {
        const float v = S[(size_t)c * ND * ND + i * ND + j] * inv_nc;
        A[i] = (i == j) ? v + 1e-6f : v;              // + eps*I (per-lane pred, no array idx)
    }

    for (int k = 0; k < ND; ++k) {
        if (j == k) {                                 // publish column k (pre-update)
            #pragma unroll
            for (int i0 = 0; i0 < ND; i0 += 4)
                *(float4*)&colk[i0] = make_float4(A[i0], A[i0+1], A[i0+2], A[i0+3]);
        }
        __builtin_amdgcn_wave_barrier();
        const float rp  = colk[j];                    // M[j][k] (lane-indexed LDS)
        const float p   = colk[k];                    // pivot (uniform LDS)
        const float ip  = 1.0f / p;
        const float sgn = (j < k) ? -1.0f : 1.0f;
        const float rowk = (j == k) ? ip : sgn * rp * ip;  // scaled row-k elem
        const float am   = (j == k) ? 0.0f : 1.0f;         // column-k pre-zero
        #pragma unroll
        for (int i0 = 0; i0 < ND; i0 += 4) {
            const float4 c4 = *(const float4*)&colk[i0];   // uniform b128
            #pragma unroll
            for (int r = 0; r < 4; ++r) {
                const int i = i0 + r;
                const float mk  = (i == k) ? 1.0f : 0.0f;  // uniform scalar mask
                const float res = A[i] * am - ((const float*)&c4)[r] * rowk;
                A[i] = res + mk * (rowk - res);            // row k gets rowk
            }
        }
        __builtin_amdgcn_wave_barrier();
    }

    // mirror Sinv into LDS for the pack gather; fuse y = Sinv*mu
    float y = 0.f;
    #pragma unroll
    for (int i0 = 0; i0 < ND; i0 += 4) {
        *(float4*)&Acol[j][i0] = make_float4(A[i0], A[i0+1], A[i0+2], A[i0+3]);
        y += A[i0]     * mu[c * ND + i0]     + A[i0 + 1] * mu[c * ND + i0 + 1]
           + A[i0 + 2] * mu[c * ND + i0 + 2] + A[i0 + 3] * mu[c * ND + i0 + 3];
    }
    cbuf[j] = -2.0f * y;                              // bvec values
    float kk = mu[c * ND + j] * y;
    #pragma unroll
    for (int off = 32; off > 0; off >>= 1) kk += __shfl_down(kk, off);
    const float kks = __shfl(kk, 0);
    if (j == 0) {
        int lab = 0;
        for (int q = 0; q < NK; ++q) if (clab[c * NK + q] != 0) lab = q;
        labf[c] = (float)lab;
    }
    __builtin_amdgcn_wave_barrier();

    // fused pack: beta = [sym-folded Sinv, b, k, 0pad] as bf16 hi/lo
    unsigned short* __restrict__ ph = Bph + (size_t)c * KP;
    unsigned short* __restrict__ pl = Bpl + (size_t)c * KP;
    #pragma unroll
    for (int t = 0; t < KP / 64; ++t) {               // 34 iters, p = t*64+j
        const int p = t * 64 + j;
        float val;
        if (p < NPAIR) {
            const int e = eop[p], d = dop[p];
            val = (e == d) ? Acol[e][e] : (Acol[d][e] + Acol[e][d]);
        } else if (p < KOFF) val = cbuf[p - BOFF];
        else if (p == KOFF)  val = kks;
        else                 val = 0.f;
        const unsigned short h = f2b(val);
        const unsigned short l = f2b(val - b2f(h));
        ph[p] = h;
        pl[p] = l;
    }
}

// ---------------- Q rows: [z_e*z_d (e<=d), z, 1, 0pad] as bf16 hi/lo ----------------
// Also zeroes this sample's d2 row (split-K gemm accumulates with atomics).
__global__ __launch_bounds__(256) void qbuild_kernel(
    const float* __restrict__ data, const int* __restrict__ eop,
    const int* __restrict__ dop, unsigned short* __restrict__ Qh,
    unsigned short* __restrict__ Ql, float* __restrict__ d2)
{
    const int s = blockIdx.x;
    __shared__ float z[ND];
    if (threadIdx.x < ND) z[threadIdx.x] = data[(size_t)s * ND + threadIdx.x];
    *(float2*)&d2[(size_t)s * NC + threadIdx.x * 2] = make_float2(0.f, 0.f);
    __syncthreads();
    for (int p = threadIdx.x; p < KP; p += 256) {
        float val;
        if (p < NPAIR)      val = z[eop[p]] * z[dop[p]];
        else if (p < KOFF)  val = z[p - BOFF];
        else if (p == KOFF) val = 1.0f;
        else                val = 0.f;
        const unsigned short h = f2b(val);
        const unsigned short l = f2b(val - b2f(h));
        Qh[(size_t)s * KP + p] = h;
        Ql[(size_t)s * KP + p] = l;
    }
}

// ---------------- d2[s][c] = Q · Beta^T via bf16x3 MFMA, split-K x4 ----------------
// Tile 32x256, 4 waves; blockIdx.z = K-slice (17 of 68 k-chunks); atomicAdd epilogue.
__global__ __launch_bounds__(256) void gemm_kernel(
    const unsigned short* __restrict__ Qh, const unsigned short* __restrict__ Ql,
    const unsigned short* __restrict__ Bph, const unsigned short* __restrict__ Bpl,
    float* __restrict__ d2)
{
    __shared__ unsigned short AhS[32][40], AlS[32][40];    // +8 pad vs 32
    __shared__ unsigned short BhS[256][40], BlS[256][40];

    const int tid  = threadIdx.x;
    const int lane = tid & 63, w = tid >> 6;
    const int quad = lane >> 4, rlo = lane & 15;
    const int m0 = blockIdx.x * 32;      // sample tile
    const int n0 = blockIdx.y * 256;     // cluster tile
    const int koff0 = blockIdx.z * KT_PER * 32;   // this block's K-slice start

    const int aplane = tid >> 7, aidx = tid & 127;
    const int arow = aidx >> 2, aseg = aidx & 3;
    const unsigned short* aSrc = (aplane ? Ql : Qh) + (size_t)(m0 + arow) * KP + aseg * 8 + koff0;
    unsigned short* aDst = (aplane ? &AlS[0][0] : &AhS[0][0]) + arow * 40 + aseg * 8;

    const unsigned short* bSrc[8];
    unsigned short* bDst[8];
    #pragma unroll
    for (int it = 0; it < 8; ++it) {
        const int idx2 = it * 256 + tid;
        const int bplane = idx2 >> 10, idx = idx2 & 1023;
        const int br = idx >> 2, bseg = idx & 3;
        bSrc[it] = (bplane ? Bpl : Bph) + (size_t)(n0 + br) * KP + bseg * 8 + koff0;
        bDst[it] = (bplane ? &BlS[0][0] : &BhS[0][0]) + br * 40 + bseg * 8;
    }

    ushort8 pa, pb[8];
    pa = *(const ushort8*)(aSrc);
    #pragma unroll
    for (int it = 0; it < 8; ++it) pb[it] = *(const ushort8*)(bSrc[it]);

    floatx4 acc[2][4] = {};

    for (int kt = 0; kt < KT_PER; ++kt) {
        __syncthreads();
        *(ushort8*)aDst = pa;
        #pragma unroll
        for (int it = 0; it < 8; ++it) *(ushort8*)bDst[it] = pb[it];
        __syncthreads();

        if (kt + 1 < KT_PER) {
            const int ko = (kt + 1) * 32;
            pa = *(const ushort8*)(aSrc + ko);
            #pragma unroll
            for (int it = 0; it < 8; ++it) pb[it] = *(const ushort8*)(bSrc[it] + ko);
        }

        short8 ah[2], al[2], bh[4], bl[4];
        #pragma unroll
        for (int i = 0; i < 2; ++i) {
            ah[i] = *(const short8*)&AhS[i * 16 + rlo][quad * 8];
            al[i] = *(const short8*)&AlS[i * 16 + rlo][quad * 8];
        }
        #pragma unroll
        for (int j = 0; j < 4; ++j) {
            const int r = w * 64 + j * 16 + rlo;
            bh[j] = *(const short8*)&BhS[r][quad * 8];
            bl[j] = *(const short8*)&BlS[r][quad * 8];
        }
        #pragma unroll
        for (int i = 0; i < 2; ++i)
            #pragma unroll
            for (int j = 0; j < 4; ++j) {
                acc[i][j] = __builtin_amdgcn_mfma_f32_16x16x32_bf16(al[i], bh[j], acc[i][j], 0, 0, 0);
                acc[i][j] = __builtin_amdgcn_mfma_f32_16x16x32_bf16(ah[i], bl[j], acc[i][j], 0, 0, 0);
                acc[i][j] = __builtin_amdgcn_mfma_f32_16x16x32_bf16(ah[i], bh[j], acc[i][j], 0, 0, 0);
            }
    }

    // C layout (verified m89): col = lane&15, row = (lane>>4)*4 + reg
    #pragma unroll
    for (int i = 0; i < 2; ++i)
        #pragma unroll
        for (int j = 0; j < 4; ++j) {
            const int m = m0 + i * 16 + quad * 4;
            const int n = n0 + w * 64 + j * 16 + rlo;
            #pragma unroll
            for (int r = 0; r < 4; ++r)
                atomicAdd(&d2[(size_t)(m + r) * NC + n], acc[i][j][r]);
        }
}

// ---------------- scores / argmaxes: one wave per sample ----------------
__global__ __launch_bounds__(64) void score_kernel(
    const float* __restrict__ d2, const float* __restrict__ labf,
    float* __restrict__ out)
{
    const int s = blockIdx.x;
    const int l = threadIdx.x;

    float numer[NK];
    #pragma unroll
    for (int q = 0; q < NK; ++q) numer[q] = 0.f;
    float denom = 0.f, gmax = -1.f;
    int gidx = 0;

    #pragma unroll
    for (int i = 0; i < NC / 256; ++i) {         // float4 per lane, index-ascending
        const int c0 = i * 256 + l * 4;
        const float4 v = *(const float4*)&d2[(size_t)s * NC + c0];
        #pragma unroll
        for (int r = 0; r < 4; ++r) {
            const int c = c0 + r;
            const float G = __expf(-0.5f * ((const float*)&v)[r]);
            denom += G;
            const int lab = (int)labf[c];
            #pragma unroll
            for (int q = 0; q < NK; ++q) numer[q] += (q == lab) ? G : 0.f;
            if (G > gmax) { gmax = G; gidx = c; }   // strict > keeps first index
        }
    }

    // wave reduction (width 64); ties -> lowest cluster index (jnp first-max)
    #pragma unroll
    for (int off = 32; off > 0; off >>= 1) {
        const float og = __shfl_down(gmax, off);
        const int   oi = __shfl_down(gidx, off);
        if (og > gmax || (og == gmax && oi < gidx)) { gmax = og; gidx = oi; }
        denom += __shfl_down(denom, off);
        #pragma unroll
        for (int q = 0; q < NK; ++q) numer[q] += __shfl_down(numer[q], off);
    }

    if (l == 0) {
        const float inv = 1.0f / (denom + 1e-12f);
        float best = -1.f; int pk = 0;
        #pragma unroll
        for (int q = 0; q < NK; ++q) {
            const float sc = numer[q] * inv;
            out[(size_t)s * NK + q] = sc;
            if (sc > best) { best = sc; pk = q; }
        }
        out[(size_t)NS * NK + s]      = (float)pk;    // pred
        out[(size_t)NS * NK + NS + s] = (float)gidx;  // clusters
    }
}

extern "C" void kernel_launch(void* const* d_in, const int* in_sizes, int n_in,
                              void* d_out, int out_size, void* d_ws, size_t ws_size,
                              hipStream_t stream)
{
    const float* data = (const float*)d_in[0];
    const float* n    = (const float*)d_in[2];
    const float* mu   = (const float*)d_in[3];
    const float* S    = (const float*)d_in[4];
    const int*   clab = (const int*)d_in[5];

    char* w = (char*)d_ws;
    unsigned short* Qh  = (unsigned short*)(w);                 // 17,825,792 B
    unsigned short* Ql  = (unsigned short*)(w + 17825792);      // 17,825,792 B
    unsigned short* Bph = (unsigned short*)(w + 35651584);      //  2,228,224 B
    unsigned short* Bpl = (unsigned short*)(w + 37879808);      //  2,228,224 B
    float* d2   = (float*)(w + 40108032);                       //  8,388,608 B
    float* labf = (float*)(w + 48496640);                       //      2,048 B
    int*   eop  = (int*)  (w + 48498688);                       //      8,320 B
    int*   dop  = (int*)  (w + 48507008);                       //      8,320 B  (end 48,515,328)

    hipLaunchKernelGGL(table_kernel, dim3(1),   dim3(64),  0, stream, eop, dop);
    hipLaunchKernelGGL(prep_kernel,  dim3(NC),  dim3(64),  0, stream,
                       S, n, mu, clab, eop, dop, Bph, Bpl, labf);
    hipLaunchKernelGGL(qbuild_kernel, dim3(NS), dim3(256), 0, stream,
                       data, eop, dop, Qh, Ql, d2);
    hipLaunchKernelGGL(gemm_kernel,  dim3(NS / 32, NC / 256, KSPLIT), dim3(256), 0, stream,
                       Qh, Ql, Bph, Bpl, d2);
    hipLaunchKernelGGL(score_kernel, dim3(NS),  dim3(64),  0, stream,
                       d2, labf, (float*)d_out);
}

// Round 9
// 216.088 us; speedup vs baseline: 1.0614x; 1.0614x over previous
//
#include <hip/hip_runtime.h>
#include <hip/hip_bf16.h>
#include <math.h>

#define NS 4096      // samples
#define NC 512       // clusters
#define ND 64        // feature dim
#define NK 10        // classes
#define NPAIR 2080   // upper-triangle pairs (e<=d) of 64x64
#define KP 2176      // 2080 + 64 (linear) + 1 (const) + 31 zero-pad; 68*32
#define BOFF 2080
#define KOFF 2144
#define KSPLIT 4
#define KT_PER (KP / 32 / KSPLIT)   // 17 k-chunks per split block

typedef __attribute__((ext_vector_type(8))) short short8;
typedef __attribute__((ext_vector_type(8))) unsigned short ushort8;
typedef __attribute__((ext_vector_type(4))) float floatx4;

__device__ inline unsigned short f2b(float x) {
    __hip_bfloat16 h = __float2bfloat16(x);           // RNE
    return __builtin_bit_cast(unsigned short, h);
}
__device__ inline float b2f(unsigned short u) {
    __hip_bfloat16 h = __builtin_bit_cast(__hip_bfloat16, u);
    return __bfloat162float(h);
}

// ---------------- pair-index tables ----------------
__global__ void table_kernel(int* __restrict__ eop, int* __restrict__ dop) {
    const int e = threadIdx.x;                        // 64 threads
    int off = e * 64 - (e * (e - 1)) / 2;             // row e starts here
    for (int d = e; d < 64; ++d) { eop[off + d - e] = e; dop[off + d - e] = d; }
}

#define FOR16(M) M(0) M(1) M(2) M(3) M(4) M(5) M(6) M(7) \
                 M(8) M(9) M(10) M(11) M(12) M(13) M(14) M(15)

// ---------------- Sigma^-1: register GJ with NAMED float4 regs + fused pack --
// R3/R7/R8 post-mortem: `float A[64]` is demoted to scratch no matter how the
// k-masking is written, because SROA runs BEFORE loop unrolling: at SROA time
// the `#pragma unroll` i-loop still has dynamic GEPs, the alloca survives, and
// the kernel runs out of L1-cached scratch (VGPR=68-72, ~85-90us, VALUBusy
// ~10%). Fix: 16 named float4 variables (no alloca exists). The (i==k) fixup
// is a v_cndmask on registers with a wave-uniform scalar condition.
// Sign identity (R7/R8-verified, absmax 0.0): in-place GJ of a symmetric
// matrix satisfies M[k][j] = (j<k?-1:+1)*M[j][k], so the row-k element comes
// from the published column-k LDS buffer at own-lane index.
__global__ __launch_bounds__(64, 1) void prep_kernel(
    const float* __restrict__ S, const float* __restrict__ n,
    const float* __restrict__ mu, const int* __restrict__ clab,
    const int* __restrict__ eop, const int* __restrict__ dop,
    unsigned short* __restrict__ Bph, unsigned short* __restrict__ Bpl,
    float* __restrict__ labf)
{
    const int c = blockIdx.x;
    const int j = threadIdx.x;                        // column owned by this lane
    __shared__ float colk[ND];                        // column-k broadcast
    __shared__ float Acol[ND][ND + 1];                // Sinv mirror for pack
    __shared__ float cbuf[ND];                        // bvec staging

    const float inv_nc = 1.0f / n[c];
    const float* __restrict__ Sc = S + (size_t)c * ND * ND + j;

#define DECL(t) float4 A##t;
    FOR16(DECL)
#undef DECL

#define LOADT(t) {                                                   \
    const float x0 = Sc[(4*t+0)*ND] * inv_nc;                        \
    const float x1 = Sc[(4*t+1)*ND] * inv_nc;                        \
    const float x2 = Sc[(4*t+2)*ND] * inv_nc;                        \
    const float x3 = Sc[(4*t+3)*ND] * inv_nc;                        \
    A##t.x = (4*t+0 == j) ? x0 + 1e-6f : x0;                         \
    A##t.y = (4*t+1 == j) ? x1 + 1e-6f : x1;                         \
    A##t.z = (4*t+2 == j) ? x2 + 1e-6f : x2;                         \
    A##t.w = (4*t+3 == j) ? x3 + 1e-6f : x3; }
    FOR16(LOADT)
#undef LOADT

    for (int k = 0; k < ND; ++k) {
        if (j == k) {                                 // publish column k (pre-update)
#define PUB(t) *(float4*)&colk[4*t] = A##t;
            FOR16(PUB)
#undef PUB
        }
        __builtin_amdgcn_wave_barrier();
        const float rp   = colk[j];                   // M[j][k] (lane-indexed LDS)
        const float p    = colk[k];                   // pivot (uniform LDS)
        const float ip   = 1.0f / p;
        const float rowk = (j == k) ? ip : ((j < k) ? -rp : rp) * ip;
        const float am   = (j == k) ? 0.0f : 1.0f;    // column-k pre-zero
#define UPD(t) {                                                     \
    const float4 c4 = *(const float4*)&colk[4*t];                    \
    const float rx = A##t.x * am - c4.x * rowk;                      \
    const float ry = A##t.y * am - c4.y * rowk;                      \
    const float rz = A##t.z * am - c4.z * rowk;                      \
    const float rw = A##t.w * am - c4.w * rowk;                      \
    A##t.x = (4*t+0 == k) ? rowk : rx;                               \
    A##t.y = (4*t+1 == k) ? rowk : ry;                               \
    A##t.z = (4*t+2 == k) ? rowk : rz;                               \
    A##t.w = (4*t+3 == k) ? rowk : rw; }
        FOR16(UPD)
#undef UPD
        __builtin_amdgcn_wave_barrier();
    }

    // mirror Sinv into LDS for the pack gather; fuse y = Sinv*mu
    float y = 0.f;
#define MIR(t) {                                                     \
    *(float4*)&Acol[j][4*t] = A##t;                                  \
    y += A##t.x * mu[c*ND + 4*t]     + A##t.y * mu[c*ND + 4*t + 1]   \
       + A##t.z * mu[c*ND + 4*t + 2] + A##t.w * mu[c*ND + 4*t + 3]; }
    FOR16(MIR)
#undef MIR
    cbuf[j] = -2.0f * y;                              // bvec values
    float kk = mu[c * ND + j] * y;
    #pragma unroll
    for (int off = 32; off > 0; off >>= 1) kk += __shfl_down(kk, off);
    const float kks = __shfl(kk, 0);
    if (j == 0) {
        int lab = 0;
        for (int q = 0; q < NK; ++q) if (clab[c * NK + q] != 0) lab = q;
        labf[c] = (float)lab;
    }
    __builtin_amdgcn_wave_barrier();

    // fused pack: beta = [sym-folded Sinv, b, k, 0pad] as bf16 hi/lo
    unsigned short* __restrict__ ph = Bph + (size_t)c * KP;
    unsigned short* __restrict__ pl = Bpl + (size_t)c * KP;
    #pragma unroll
    for (int t = 0; t < KP / 64; ++t) {               // 34 iters, p = t*64+j
        const int p = t * 64 + j;
        float val;
        if (p < NPAIR) {
            const int e = eop[p], d = dop[p];
            val = (e == d) ? Acol[e][e] : (Acol[d][e] + Acol[e][d]);
        } else if (p < KOFF) val = cbuf[p - BOFF];
        else if (p == KOFF)  val = kks;
        else                 val = 0.f;
        const unsigned short h = f2b(val);
        const unsigned short l = f2b(val - b2f(h));
        ph[p] = h;
        pl[p] = l;
    }
}

// ---------------- Q rows: [z_e*z_d (e<=d), z, 1, 0pad] as bf16 hi/lo ----------------
// Also zeroes this sample's d2 row (split-K gemm accumulates with atomics).
__global__ __launch_bounds__(256) void qbuild_kernel(
    const float* __restrict__ data, const int* __restrict__ eop,
    const int* __restrict__ dop, unsigned short* __restrict__ Qh,
    unsigned short* __restrict__ Ql, float* __restrict__ d2)
{
    const int s = blockIdx.x;
    __shared__ float z[ND];
    if (threadIdx.x < ND) z[threadIdx.x] = data[(size_t)s * ND + threadIdx.x];
    *(float2*)&d2[(size_t)s * NC + threadIdx.x * 2] = make_float2(0.f, 0.f);
    __syncthreads();
    for (int p = threadIdx.x; p < KP; p += 256) {
        float val;
        if (p < NPAIR)      val = z[eop[p]] * z[dop[p]];
        else if (p < KOFF)  val = z[p - BOFF];
        else if (p == KOFF) val = 1.0f;
        else                val = 0.f;
        const unsigned short h = f2b(val);
        const unsigned short l = f2b(val - b2f(h));
        Qh[(size_t)s * KP + p] = h;
        Ql[(size_t)s * KP + p] = l;
    }
}

// ---------------- d2[s][c] = Q · Beta^T via bf16x3 MFMA, split-K x4 ----------------
// Tile 32x256, 4 waves; blockIdx.z = K-slice (17 of 68 k-chunks); atomicAdd epilogue.
__global__ __launch_bounds__(256) void gemm_kernel(
    const unsigned short* __restrict__ Qh, const unsigned short* __restrict__ Ql,
    const unsigned short* __restrict__ Bph, const unsigned short* __restrict__ Bpl,
    float* __restrict__ d2)
{
    __shared__ unsigned short AhS[32][40], AlS[32][40];    // +8 pad vs 32
    __shared__ unsigned short BhS[256][40], BlS[256][40];

    const int tid  = threadIdx.x;
    const int lane = tid & 63, w = tid >> 6;
    const int quad = lane >> 4, rlo = lane & 15;
    const int m0 = blockIdx.x * 32;      // sample tile
    const int n0 = blockIdx.y * 256;     // cluster tile
    const int koff0 = blockIdx.z * KT_PER * 32;   // this block's K-slice start

    const int aplane = tid >> 7, aidx = tid & 127;
    const int arow = aidx >> 2, aseg = aidx & 3;
    const unsigned short* aSrc = (aplane ? Ql : Qh) + (size_t)(m0 + arow) * KP + aseg * 8 + koff0;
    unsigned short* aDst = (aplane ? &AlS[0][0] : &AhS[0][0]) + arow * 40 + aseg * 8;

    const unsigned short* bSrc[8];
    unsigned short* bDst[8];
    #pragma unroll
    for (int it = 0; it < 8; ++it) {
        const int idx2 = it * 256 + tid;
        const int bplane = idx2 >> 10, idx = idx2 & 1023;
        const int br = idx >> 2, bseg = idx & 3;
        bSrc[it] = (bplane ? Bpl : Bph) + (size_t)(n0 + br) * KP + bseg * 8 + koff0;
        bDst[it] = (bplane ? &BlS[0][0] : &BhS[0][0]) + br * 40 + bseg * 8;
    }

    ushort8 pa, pb[8];
    pa = *(const ushort8*)(aSrc);
    #pragma unroll
    for (int it = 0; it < 8; ++it) pb[it] = *(const ushort8*)(bSrc[it]);

    floatx4 acc[2][4] = {};

    for (int kt = 0; kt < KT_PER; ++kt) {
        __syncthreads();
        *(ushort8*)aDst = pa;
        #pragma unroll
        for (int it = 0; it < 8; ++it) *(ushort8*)bDst[it] = pb[it];
        __syncthreads();

        if (kt + 1 < KT_PER) {
            const int ko = (kt + 1) * 32;
            pa = *(const ushort8*)(aSrc + ko);
            #pragma unroll
            for (int it = 0; it < 8; ++it) pb[it] = *(const ushort8*)(bSrc[it] + ko);
        }

        short8 ah[2], al[2], bh[4], bl[4];
        #pragma unroll
        for (int i = 0; i < 2; ++i) {
            ah[i] = *(const short8*)&AhS[i * 16 + rlo][quad * 8];
            al[i] = *(const short8*)&AlS[i * 16 + rlo][quad * 8];
        }
        #pragma unroll
        for (int j = 0; j < 4; ++j) {
            const int r = w * 64 + j * 16 + rlo;
            bh[j] = *(const short8*)&BhS[r][quad * 8];
            bl[j] = *(const short8*)&BlS[r][quad * 8];
        }
        #pragma unroll
        for (int i = 0; i < 2; ++i)
            #pragma unroll
            for (int j = 0; j < 4; ++j) {
                acc[i][j] = __builtin_amdgcn_mfma_f32_16x16x32_bf16(al[i], bh[j], acc[i][j], 0, 0, 0);
                acc[i][j] = __builtin_amdgcn_mfma_f32_16x16x32_bf16(ah[i], bl[j], acc[i][j], 0, 0, 0);
                acc[i][j] = __builtin_amdgcn_mfma_f32_16x16x32_bf16(ah[i], bh[j], acc[i][j], 0, 0, 0);
            }
    }

    // C layout (verified m89): col = lane&15, row = (lane>>4)*4 + reg
    #pragma unroll
    for (int i = 0; i < 2; ++i)
        #pragma unroll
        for (int j = 0; j < 4; ++j) {
            const int m = m0 + i * 16 + quad * 4;
            const int n = n0 + w * 64 + j * 16 + rlo;
            #pragma unroll
            for (int r = 0; r < 4; ++r)
                atomicAdd(&d2[(size_t)(m + r) * NC + n], acc[i][j][r]);
        }
}

// ---------------- scores / argmaxes: one wave per sample ----------------
__global__ __launch_bounds__(64) void score_kernel(
    const float* __restrict__ d2, const float* __restrict__ labf,
    float* __restrict__ out)
{
    const int s = blockIdx.x;
    const int l = threadIdx.x;

    float numer[NK];
    #pragma unroll
    for (int q = 0; q < NK; ++q) numer[q] = 0.f;
    float denom = 0.f, gmax = -1.f;
    int gidx = 0;

    #pragma unroll
    for (int i = 0; i < NC / 256; ++i) {         // float4 per lane, index-ascending
        const int c0 = i * 256 + l * 4;
        const float4 v = *(const float4*)&d2[(size_t)s * NC + c0];
        #pragma unroll
        for (int r = 0; r < 4; ++r) {
            const int c = c0 + r;
            const float G = __expf(-0.5f * ((const float*)&v)[r]);
            denom += G;
            const int lab = (int)labf[c];
            #pragma unroll
            for (int q = 0; q < NK; ++q) numer[q] += (q == lab) ? G : 0.f;
            if (G > gmax) { gmax = G; gidx = c; }   // strict > keeps first index
        }
    }

    // wave reduction (width 64); ties -> lowest cluster index (jnp first-max)
    #pragma unroll
    for (int off = 32; off > 0; off >>= 1) {
        const float og = __shfl_down(gmax, off);
        const int   oi = __shfl_down(gidx, off);
        if (og > gmax || (og == gmax && oi < gidx)) { gmax = og; gidx = oi; }
        denom += __shfl_down(denom, off);
        #pragma unroll
        for (int q = 0; q < NK; ++q) numer[q] += __shfl_down(numer[q], off);
    }

    if (l == 0) {
        const float inv = 1.0f / (denom + 1e-12f);
        float best = -1.f; int pk = 0;
        #pragma unroll
        for (int q = 0; q < NK; ++q) {
            const float sc = numer[q] * inv;
            out[(size_t)s * NK + q] = sc;
            if (sc > best) { best = sc; pk = q; }
        }
        out[(size_t)NS * NK + s]      = (float)pk;    // pred
        out[(size_t)NS * NK + NS + s] = (float)gidx;  // clusters
    }
}

extern "C" void kernel_launch(void* const* d_in, const int* in_sizes, int n_in,
                              void* d_out, int out_size, void* d_ws, size_t ws_size,
                              hipStream_t stream)
{
    const float* data = (const float*)d_in[0];
    const float* n    = (const float*)d_in[2];
    const float* mu   = (const float*)d_in[3];
    const float* S    = (const float*)d_in[4];
    const int*   clab = (const int*)d_in[5];

    char* w = (char*)d_ws;
    unsigned short* Qh  = (unsigned short*)(w);                 // 17,825,792 B
    unsigned short* Ql  = (unsigned short*)(w + 17825792);      // 17,825,792 B
    unsigned short* Bph = (unsigned short*)(w + 35651584);      //  2,228,224 B
    unsigned short* Bpl = (unsigned short*)(w + 37879808);      //  2,228,224 B
    float* d2   = (float*)(w + 40108032);                       //  8,388,608 B
    float* labf = (float*)(w + 48496640);                       //      2,048 B
    int*   eop  = (int*)  (w + 48498688);                       //      8,320 B
    int*   dop  = (int*)  (w + 48507008);                       //      8,320 B  (end 48,515,328)

    hipLaunchKernelGGL(table_kernel, dim3(1),   dim3(64),  0, stream, eop, dop);
    hipLaunchKernelGGL(prep_kernel,  dim3(NC),  dim3(64),  0, stream,
                       S, n, mu, clab, eop, dop, Bph, Bpl, labf);
    hipLaunchKernelGGL(qbuild_kernel, dim3(NS), dim3(256), 0, stream,
                       data, eop, dop, Qh, Ql, d2);
    hipLaunchKernelGGL(gemm_kernel,  dim3(NS / 32, NC / 256, KSPLIT), dim3(256), 0, stream,
                       Qh, Ql, Bph, Bpl, d2);
    hipLaunchKernelGGL(score_kernel, dim3(NS),  dim3(64),  0, stream,
                       d2, labf, (float*)d_out);
}

// Round 10
// 197.605 us; speedup vs baseline: 1.1607x; 1.0935x over previous
//
#include <hip/hip_runtime.h>
#include <hip/hip_bf16.h>
#include <math.h>

#define NS 4096      // samples
#define NC 512       // clusters
#define ND 64        // feature dim
#define NK 10        // classes
#define NPAIR 2080   // upper-triangle pairs (e<=d) of 64x64
#define KP 2176      // 2080 + 64 (linear) + 1 (const) + 31 zero-pad; 68*32
#define BOFF 2080
#define KOFF 2144
#define KSPLIT 4
#define KT_PER (KP / 32 / KSPLIT)   // 17 k-chunks per split block

typedef __attribute__((ext_vector_type(8))) short short8;
typedef __attribute__((ext_vector_type(8))) unsigned short ushort8;
typedef __attribute__((ext_vector_type(4))) float floatx4;

__device__ inline unsigned short f2b(float x) {
    __hip_bfloat16 h = __float2bfloat16(x);           // RNE
    return __builtin_bit_cast(unsigned short, h);
}
__device__ inline float b2f(unsigned short u) {
    __hip_bfloat16 h = __builtin_bit_cast(__hip_bfloat16, u);
    return __bfloat162float(h);
}

// ---------------- pair-index tables ----------------
__global__ void table_kernel(int* __restrict__ eop, int* __restrict__ dop) {
    const int e = threadIdx.x;                        // 64 threads
    int off = e * 64 - (e * (e - 1)) / 2;             // row e starts here
    for (int d = e; d < 64; ++d) { eop[off + d - e] = e; dop[off + d - e] = d; }
}

#define FOR16(M) M(0) M(1) M(2) M(3) M(4) M(5) M(6) M(7) \
                 M(8) M(9) M(10) M(11) M(12) M(13) M(14) M(15)

// ---------------- fused prep (Sigma^-1 + beta pack) and qbuild --------------
// Blocks 0..NC-1: wave-per-cluster register GJ (named float4 regs, R9) with
// the R10 fix: 16 NAMED preload temps force ~64 extra live VGPRs so all 16
// colk ds_read_b128 issue before any FMA (R9: VGPR=72 left 8 spare regs ->
// reads serialized at full LDS latency, 71us, VALUBusy 10%).
// Blocks NC..NC+NS-1: qbuild (independent of prep; fused to overlap prep's
// serial chains behind qbuild's streaming blocks).
__global__ __launch_bounds__(256, 1) void prep_qbuild_kernel(
    const float* __restrict__ S, const float* __restrict__ n,
    const float* __restrict__ mu, const int* __restrict__ clab,
    const float* __restrict__ data, const int* __restrict__ eop,
    const int* __restrict__ dop, unsigned short* __restrict__ Bph,
    unsigned short* __restrict__ Bpl, unsigned short* __restrict__ Qh,
    unsigned short* __restrict__ Ql, float* __restrict__ d2,
    float* __restrict__ labf)
{
    __shared__ float smem[ND * (ND + 1) + 2 * ND];
    float* __restrict__ AcolS = smem;                 // [64][65] Sinv mirror
    float* __restrict__ colk  = smem + ND * (ND + 1); // column-k broadcast / z
    float* __restrict__ cbuf  = colk + ND;            // bvec staging

    if (blockIdx.x >= NC) {
        // ---------------- qbuild role ----------------
        const int s = blockIdx.x - NC;
        float* __restrict__ z = colk;
        if (threadIdx.x < ND) z[threadIdx.x] = data[(size_t)s * ND + threadIdx.x];
        *(float2*)&d2[(size_t)s * NC + threadIdx.x * 2] = make_float2(0.f, 0.f);
        __syncthreads();
        for (int p = threadIdx.x; p < KP; p += 256) {
            float val;
            if (p < NPAIR)      val = z[eop[p]] * z[dop[p]];
            else if (p < KOFF)  val = z[p - BOFF];
            else if (p == KOFF) val = 1.0f;
            else                val = 0.f;
            const unsigned short h = f2b(val);
            const unsigned short l = f2b(val - b2f(h));
            Qh[(size_t)s * KP + p] = h;
            Ql[(size_t)s * KP + p] = l;
        }
        return;
    }

    // ---------------- prep role: wave 0 only (no __syncthreads below) -------
    if (threadIdx.x >= 64) return;
    const int c = blockIdx.x;
    const int j = threadIdx.x;                        // column owned by this lane

    const float inv_nc = 1.0f / n[c];
    const float* __restrict__ Sc = S + (size_t)c * ND * ND + j;

#define DECL(t) float4 A##t;
    FOR16(DECL)
#undef DECL

#define LOADT(t) {                                                   \
    const float x0 = Sc[(4*t+0)*ND] * inv_nc;                        \
    const float x1 = Sc[(4*t+1)*ND] * inv_nc;                        \
    const float x2 = Sc[(4*t+2)*ND] * inv_nc;                        \
    const float x3 = Sc[(4*t+3)*ND] * inv_nc;                        \
    A##t.x = (4*t+0 == j) ? x0 + 1e-6f : x0;                         \
    A##t.y = (4*t+1 == j) ? x1 + 1e-6f : x1;                         \
    A##t.z = (4*t+2 == j) ? x2 + 1e-6f : x2;                         \
    A##t.w = (4*t+3 == j) ? x3 + 1e-6f : x3; }
    FOR16(LOADT)
#undef LOADT

    for (int k = 0; k < ND; ++k) {
        if (j == k) {                                 // publish column k (pre-update)
#define PUB(t) *(float4*)&colk[4*t] = A##t;
            FOR16(PUB)
#undef PUB
        }
        __builtin_amdgcn_wave_barrier();
        const float rp   = colk[j];                   // M[j][k] (lane-indexed LDS)
        const float p    = colk[k];                   // pivot (uniform LDS)
        // preload ALL colk chunks into named regs: 16 independent b128 reads
        // in flight -> one lgkmcnt drain instead of 16 serialized latencies.
#define RD(t) const float4 k4_##t = *(const float4*)&colk[4*t];
        FOR16(RD)
#undef RD
        const float ip   = 1.0f / p;
        const float rowk = (j == k) ? ip : ((j < k) ? -rp : rp) * ip;
        const float am   = (j == k) ? 0.0f : 1.0f;    // column-k pre-zero
#define UPD(t) {                                                     \
    const float rx = A##t.x * am - k4_##t.x * rowk;                  \
    const float ry = A##t.y * am - k4_##t.y * rowk;                  \
    const float rz = A##t.z * am - k4_##t.z * rowk;                  \
    const float rw = A##t.w * am - k4_##t.w * rowk;                  \
    A##t.x = (4*t+0 == k) ? rowk : rx;                               \
    A##t.y = (4*t+1 == k) ? rowk : ry;                               \
    A##t.z = (4*t+2 == k) ? rowk : rz;                               \
    A##t.w = (4*t+3 == k) ? rowk : rw; }
        FOR16(UPD)
#undef UPD
        __builtin_amdgcn_wave_barrier();
    }

    // mirror Sinv into LDS for the pack gather; fuse y = Sinv*mu
    float y = 0.f;
#define MIR(t) {                                                     \
    *(float4*)&AcolS[j * (ND + 1) + 4*t] = A##t;                     \
    y += A##t.x * mu[c*ND + 4*t]     + A##t.y * mu[c*ND + 4*t + 1]   \
       + A##t.z * mu[c*ND + 4*t + 2] + A##t.w * mu[c*ND + 4*t + 3]; }
    FOR16(MIR)
#undef MIR
    cbuf[j] = -2.0f * y;                              // bvec values
    float kk = mu[c * ND + j] * y;
    #pragma unroll
    for (int off = 32; off > 0; off >>= 1) kk += __shfl_down(kk, off);
    const float kks = __shfl(kk, 0);
    if (j == 0) {
        int lab = 0;
        for (int q = 0; q < NK; ++q) if (clab[c * NK + q] != 0) lab = q;
        labf[c] = (float)lab;
    }
    __builtin_amdgcn_wave_barrier();

    // fused pack: beta = [sym-folded Sinv, b, k, 0pad] as bf16 hi/lo
    unsigned short* __restrict__ ph = Bph + (size_t)c * KP;
    unsigned short* __restrict__ pl = Bpl + (size_t)c * KP;
    #pragma unroll
    for (int t = 0; t < KP / 64; ++t) {               // 34 iters, p = t*64+j
        const int p = t * 64 + j;
        float val;
        if (p < NPAIR) {
            const int e = eop[p], d = dop[p];
            val = (e == d) ? AcolS[e * (ND + 1) + e]
                           : (AcolS[d * (ND + 1) + e] + AcolS[e * (ND + 1) + d]);
        } else if (p < KOFF) val = cbuf[p - BOFF];
        else if (p == KOFF)  val = kks;
        else                 val = 0.f;
        const unsigned short h = f2b(val);
        const unsigned short l = f2b(val - b2f(h));
        ph[p] = h;
        pl[p] = l;
    }
}

// ---------------- d2[s][c] = Q · Beta^T via bf16x3 MFMA, split-K x4 ----------------
// Tile 32x256, 4 waves; blockIdx.z = K-slice (17 of 68 k-chunks); atomicAdd epilogue.
__global__ __launch_bounds__(256) void gemm_kernel(
    const unsigned short* __restrict__ Qh, const unsigned short* __restrict__ Ql,
    const unsigned short* __restrict__ Bph, const unsigned short* __restrict__ Bpl,
    float* __restrict__ d2)
{
    __shared__ unsigned short AhS[32][40], AlS[32][40];    // +8 pad vs 32
    __shared__ unsigned short BhS[256][40], BlS[256][40];

    const int tid  = threadIdx.x;
    const int lane = tid & 63, w = tid >> 6;
    const int quad = lane >> 4, rlo = lane & 15;
    const int m0 = blockIdx.x * 32;      // sample tile
    const int n0 = blockIdx.y * 256;     // cluster tile
    const int koff0 = blockIdx.z * KT_PER * 32;   // this block's K-slice start

    const int aplane = tid >> 7, aidx = tid & 127;
    const int arow = aidx >> 2, aseg = aidx & 3;
    const unsigned short* aSrc = (aplane ? Ql : Qh) + (size_t)(m0 + arow) * KP + aseg * 8 + koff0;
    unsigned short* aDst = (aplane ? &AlS[0][0] : &AhS[0][0]) + arow * 40 + aseg * 8;

    const unsigned short* bSrc[8];
    unsigned short* bDst[8];
    #pragma unroll
    for (int it = 0; it < 8; ++it) {
        const int idx2 = it * 256 + tid;
        const int bplane = idx2 >> 10, idx = idx2 & 1023;
        const int br = idx >> 2, bseg = idx & 3;
        bSrc[it] = (bplane ? Bpl : Bph) + (size_t)(n0 + br) * KP + bseg * 8 + koff0;
        bDst[it] = (bplane ? &BlS[0][0] : &BhS[0][0]) + br * 40 + bseg * 8;
    }

    ushort8 pa, pb[8];
    pa = *(const ushort8*)(aSrc);
    #pragma unroll
    for (int it = 0; it < 8; ++it) pb[it] = *(const ushort8*)(bSrc[it]);

    floatx4 acc[2][4] = {};

    for (int kt = 0; kt < KT_PER; ++kt) {
        __syncthreads();
        *(ushort8*)aDst = pa;
        #pragma unroll
        for (int it = 0; it < 8; ++it) *(ushort8*)bDst[it] = pb[it];
        __syncthreads();

        if (kt + 1 < KT_PER) {
            const int ko = (kt + 1) * 32;
            pa = *(const ushort8*)(aSrc + ko);
            #pragma unroll
            for (int it = 0; it < 8; ++it) pb[it] = *(const ushort8*)(bSrc[it] + ko);
        }

        short8 ah[2], al[2], bh[4], bl[4];
        #pragma unroll
        for (int i = 0; i < 2; ++i) {
            ah[i] = *(const short8*)&AhS[i * 16 + rlo][quad * 8];
            al[i] = *(const short8*)&AlS[i * 16 + rlo][quad * 8];
        }
        #pragma unroll
        for (int j = 0; j < 4; ++j) {
            const int r = w * 64 + j * 16 + rlo;
            bh[j] = *(const short8*)&BhS[r][quad * 8];
            bl[j] = *(const short8*)&BlS[r][quad * 8];
        }
        #pragma unroll
        for (int i = 0; i < 2; ++i)
            #pragma unroll
            for (int j = 0; j < 4; ++j) {
                acc[i][j] = __builtin_amdgcn_mfma_f32_16x16x32_bf16(al[i], bh[j], acc[i][j], 0, 0, 0);
                acc[i][j] = __builtin_amdgcn_mfma_f32_16x16x32_bf16(ah[i], bl[j], acc[i][j], 0, 0, 0);
                acc[i][j] = __builtin_amdgcn_mfma_f32_16x16x32_bf16(ah[i], bh[j], acc[i][j], 0, 0, 0);
            }
    }

    // C layout (verified m89): col = lane&15, row = (lane>>4)*4 + reg
    #pragma unroll
    for (int i = 0; i < 2; ++i)
        #pragma unroll
        for (int j = 0; j < 4; ++j) {
            const int m = m0 + i * 16 + quad * 4;
            const int n = n0 + w * 64 + j * 16 + rlo;
            #pragma unroll
            for (int r = 0; r < 4; ++r)
                atomicAdd(&d2[(size_t)(m + r) * NC + n], acc[i][j][r]);
        }
}

// ---------------- scores / argmaxes: one wave per sample ----------------
__global__ __launch_bounds__(64) void score_kernel(
    const float* __restrict__ d2, const float* __restrict__ labf,
    float* __restrict__ out)
{
    const int s = blockIdx.x;
    const int l = threadIdx.x;

    float numer[NK];
    #pragma unroll
    for (int q = 0; q < NK; ++q) numer[q] = 0.f;
    float denom = 0.f, gmax = -1.f;
    int gidx = 0;

    #pragma unroll
    for (int i = 0; i < NC / 256; ++i) {         // float4 per lane, index-ascending
        const int c0 = i * 256 + l * 4;
        const float4 v = *(const float4*)&d2[(size_t)s * NC + c0];
        #pragma unroll
        for (int r = 0; r < 4; ++r) {
            const int c = c0 + r;
            const float G = __expf(-0.5f * ((const float*)&v)[r]);
            denom += G;
            const int lab = (int)labf[c];
            #pragma unroll
            for (int q = 0; q < NK; ++q) numer[q] += (q == lab) ? G : 0.f;
            if (G > gmax) { gmax = G; gidx = c; }   // strict > keeps first index
        }
    }

    // wave reduction (width 64); ties -> lowest cluster index (jnp first-max)
    #pragma unroll
    for (int off = 32; off > 0; off >>= 1) {
        const float og = __shfl_down(gmax, off);
        const int   oi = __shfl_down(gidx, off);
        if (og > gmax || (og == gmax && oi < gidx)) { gmax = og; gidx = oi; }
        denom += __shfl_down(denom, off);
        #pragma unroll
        for (int q = 0; q < NK; ++q) numer[q] += __shfl_down(numer[q], off);
    }

    if (l == 0) {
        const float inv = 1.0f / (denom + 1e-12f);
        float best = -1.f; int pk = 0;
        #pragma unroll
        for (int q = 0; q < NK; ++q) {
            const float sc = numer[q] * inv;
            out[(size_t)s * NK + q] = sc;
            if (sc > best) { best = sc; pk = q; }
        }
        out[(size_t)NS * NK + s]      = (float)pk;    // pred
        out[(size_t)NS * NK + NS + s] = (float)gidx;  // clusters
    }
}

extern "C" void kernel_launch(void* const* d_in, const int* in_sizes, int n_in,
                              void* d_out, int out_size, void* d_ws, size_t ws_size,
                              hipStream_t stream)
{
    const float* data = (const float*)d_in[0];
    const float* n    = (const float*)d_in[2];
    const float* mu   = (const float*)d_in[3];
    const float* S    = (const float*)d_in[4];
    const int*   clab = (const int*)d_in[5];

    char* w = (char*)d_ws;
    unsigned short* Qh  = (unsigned short*)(w);                 // 17,825,792 B
    unsigned short* Ql  = (unsigned short*)(w + 17825792);      // 17,825,792 B
    unsigned short* Bph = (unsigned short*)(w + 35651584);      //  2,228,224 B
    unsigned short* Bpl = (unsigned short*)(w + 37879808);      //  2,228,224 B
    float* d2   = (float*)(w + 40108032);                       //  8,388,608 B
    float* labf = (float*)(w + 48496640);                       //      2,048 B
    int*   eop  = (int*)  (w + 48498688);                       //      8,320 B
    int*   dop  = (int*)  (w + 48507008);                       //      8,320 B  (end 48,515,328)

    hipLaunchKernelGGL(table_kernel, dim3(1),   dim3(64),  0, stream, eop, dop);
    hipLaunchKernelGGL(prep_qbuild_kernel, dim3(NC + NS), dim3(256), 0, stream,
                       S, n, mu, clab, data, eop, dop, Bph, Bpl, Qh, Ql, d2, labf);
    hipLaunchKernelGGL(gemm_kernel,  dim3(NS / 32, NC / 256, KSPLIT), dim3(256), 0, stream,
                       Qh, Ql, Bph, Bpl, d2);
    hipLaunchKernelGGL(score_kernel, dim3(NS),  dim3(64),  0, stream,
                       d2, labf, (float*)d_out);
}